// Round 10
// baseline (88.124 us; speedup 1.0000x reference)
//
#include <hip/hip_runtime.h>
#include <hip/hip_bf16.h>

// CFAR via summed-area table — R16: R15 + the SAME chunked XCD swizzle on
// sat (producer) as on final (consumer), so Q rows are written and re-read
// in the same XCD's L2. R15's consumer-only swizzle was neutral because
// sat's round-robin dispatch striped Q rows across all 8 non-coherent L2s.
//   sat     : per 4-row segment (1024 blocks, swizzled): 4 waves compute row
//             prefixes P[0..3] in LDS; one barrier; column-accumulate
//             quad-cols; write segment-local SAT Q (float4). [R13-proven]
//   segscan : SP[img][s][c] = exclusive prefix over segments of Q's segment-
//             last rows. [R13-proven]
//   final   : stage Qg rows (Q + SP fold) for hi1/lo1 then hi3/lo3 through
//             32 KB LDS; SAT window math. [R13-proven body; swizzled blockIdx]
// BG_AREA = 321^2-161^2 = 77120 ; FRONT_DIV = 161^2*1.8 = 46657.8

#define IMG 4
#define H 1024
#define W 1024
#define SEGR 4
#define NSEG 256                   // H / SEGR

// ------- Kernel 1: row prefix + segment-local column prefix (SAT) ----------
__global__ __launch_bounds__(256) void sat_kernel(const float* __restrict__ x,
                                                  float* __restrict__ Q) {
    __shared__ float P[4][W];        // 16384 B — per-wave row prefix
    const int wave = threadIdx.x >> 6;
    const int lane = threadIdx.x & 63;
    const int tid  = threadIdx.x;
    // chunked XCD swizzle: 1024 blocks = 8 XCDs x 128-chunk (bijective);
    // MUST match final_kernel's mapping for producer/consumer L2 locality.
    const int lb   = ((blockIdx.x & 7) << 7) + (blockIdx.x >> 3);
    const size_t rowbase = (size_t)lb << 2;   // flat rows over images

    // ---- phase 1: row prefix into LDS (per wave, own row)
    {
        const float4* xr = reinterpret_cast<const float4*>(x + (rowbase + wave) * W);
        float v[16];
        float4 a0 = xr[(lane << 2) + 0];
        float4 a1 = xr[(lane << 2) + 1];
        float4 a2 = xr[(lane << 2) + 2];
        float4 a3 = xr[(lane << 2) + 3];
        v[0]=a0.x; v[1]=a0.y; v[2]=a0.z; v[3]=a0.w;
        v[4]=a1.x; v[5]=a1.y; v[6]=a1.z; v[7]=a1.w;
        v[8]=a2.x; v[9]=a2.y; v[10]=a2.z; v[11]=a2.w;
        v[12]=a3.x; v[13]=a3.y; v[14]=a3.z; v[15]=a3.w;
        float s = 0.f;
#pragma unroll
        for (int j = 0; j < 16; ++j) { s += v[j]; v[j] = s; }
        float t = s;
#pragma unroll
        for (int d = 1; d < 64; d <<= 1) {
            float u = __shfl_up(t, d, 64);
            if (lane >= d) t += u;
        }
        const float off = t - s;        // exclusive prefix of lane totals
#pragma unroll
        for (int j = 0; j < 16; ++j) v[j] += off;

        float4* Pr = reinterpret_cast<float4*>(P[wave]);
        Pr[(lane << 2) + 0] = make_float4(v[0], v[1], v[2], v[3]);
        Pr[(lane << 2) + 1] = make_float4(v[4], v[5], v[6], v[7]);
        Pr[(lane << 2) + 2] = make_float4(v[8], v[9], v[10], v[11]);
        Pr[(lane << 2) + 3] = make_float4(v[12], v[13], v[14], v[15]);
    }
    __syncthreads();   // the only barrier

    // ---- phase 2: column prefix over the 4 rows; float4 LDS reads + stores
    float4 acc = make_float4(0.f, 0.f, 0.f, 0.f);
    float4* Qo = reinterpret_cast<float4*>(Q) + (rowbase << 8) + tid;
#pragma unroll
    for (int rr = 0; rr < SEGR; ++rr) {
        const float4 h = reinterpret_cast<const float4*>(P[rr])[tid];
        acc.x += h.x; acc.y += h.y; acc.z += h.z; acc.w += h.w;
        Qo[(size_t)rr << 8] = acc;
    }
}

// ------- Kernel 2: exclusive scan of segment totals per column -------------
// Seg total of seg t = Q row (4t+3). Block = (img, 64-col group); wave w owns
// segs 64w..64w+63 in registers (coalesced 256 B loads), in-lane exclusive
// scan, cross-wave fixup via LDS. 64 blocks x 256.
__global__ __launch_bounds__(256) void segscan_kernel(const float* __restrict__ Q,
                                                      float* __restrict__ SP) {
    __shared__ float T[4][64];
    const int wave = threadIdx.x >> 6;
    const int lane = threadIdx.x & 63;
    const int img  = blockIdx.x >> 4;                    // 0..3
    const int col  = ((blockIdx.x & 15) << 6) + lane;    // 0..1023

    const float* Qi = Q + ((size_t)img << 20);
    float v[64];
#pragma unroll
    for (int s = 0; s < 64; ++s) {
        const int seg = (wave << 6) + s;
        v[s] = Qi[((size_t)((seg << 2) + 3) << 10) + col];
    }
    float run = 0.f;
#pragma unroll
    for (int s = 0; s < 64; ++s) { const float t = v[s]; v[s] = run; run += t; }
    T[wave][lane] = run;
    __syncthreads();
    float off = 0.f;
    for (int w = 0; w < wave; ++w) off += T[w][lane];    // wave-uniform trip
    float* SPo = SP + ((size_t)img << 18) + col;
#pragma unroll
    for (int s = 0; s < 64; ++s)
        SPo[(size_t)(((wave << 6) + s)) << 10] = v[s] + off;
}

// ------- Kernel 3: final — SAT window diffs ---------------------------------
// Block = (img, 4-row group) after chunked XCD swizzle; 256 threads, 32 KB
// LDS. Two stage+math passes [R13-proven body]: pass A stages Qg rows
// {r0+80+i, r0-81+i} (SP folded; neg rows = 0), computes front; pass B
// stages {r0+160+i, r0-161+i}, computes allsum and out.
__global__ __launch_bounds__(256) void final_kernel(const float* __restrict__ Q,
                                                    const float* __restrict__ SP,
                                                    float* __restrict__ out) {
    __shared__ float S[8][W];        // 32768 B
    const int tid = threadIdx.x;
    // chunked XCD swizzle: 1024 blocks = 8 XCDs x 128-chunk (bijective)
    const int lb  = ((blockIdx.x & 7) << 7) + (blockIdx.x >> 3);
    const int img = lb >> 8;
    const int r0  = (lb & 255) << 2;

    const float4* Q4  = reinterpret_cast<const float4*>(Q)  + ((size_t)img << 18);
    const float4* SP4 = reinterpret_cast<const float4*>(SP) + ((size_t)img << 16);
    float4* S4 = reinterpret_cast<float4*>(&S[0][0]);

    // ---- pass A: stage hi1 rows (slots 0..3) and lo1 rows (slots 4..7)
#pragma unroll
    for (int i = 0; i < 4; ++i) {
        {   // hi1 = min(r0+80+i, 1023)  (always >= 0)
            const int row = min(r0 + 80 + i, H - 1);
            const float4 a = Q4[((size_t)row << 8) + tid];
            const float4 b = SP4[((size_t)(row >> 2) << 8) + tid];
            S4[(i << 8) + tid] = make_float4(a.x + b.x, a.y + b.y, a.z + b.z, a.w + b.w);
        }
        {   // lo1 = r0-81+i  (may be negative -> zeros)
            const int row = r0 - 81 + i;
            float4 vv = make_float4(0.f, 0.f, 0.f, 0.f);
            if (row >= 0) {
                const float4 a = Q4[((size_t)row << 8) + tid];
                const float4 b = SP4[((size_t)(row >> 2) << 8) + tid];
                vv = make_float4(a.x + b.x, a.y + b.y, a.z + b.z, a.w + b.w);
            }
            S4[((4 + i) << 8) + tid] = vv;
        }
    }
    __syncthreads();

    float fr[4][4];
#pragma unroll
    for (int i = 0; i < 4; ++i) {
#pragma unroll
        for (int j = 0; j < 4; ++j) {
            const int c  = tid + (j << 8);
            const int kp = min(c + 80, W - 1);
            const int km = c - 81;
            const float m = (km >= 0) ? 1.f : 0.f;
            const int k  = max(km, 0);
            fr[i][j] = (S[i][kp] - m * S[i][k]) - (S[4 + i][kp] - m * S[4 + i][k]);
        }
    }
    __syncthreads();   // before overwriting S

    // ---- pass B: stage hi3 rows (slots 0..3) and lo3 rows (slots 4..7)
#pragma unroll
    for (int i = 0; i < 4; ++i) {
        {   // hi3 = min(r0+160+i, 1023)
            const int row = min(r0 + 160 + i, H - 1);
            const float4 a = Q4[((size_t)row << 8) + tid];
            const float4 b = SP4[((size_t)(row >> 2) << 8) + tid];
            S4[(i << 8) + tid] = make_float4(a.x + b.x, a.y + b.y, a.z + b.z, a.w + b.w);
        }
        {   // lo3 = r0-161+i
            const int row = r0 - 161 + i;
            float4 vv = make_float4(0.f, 0.f, 0.f, 0.f);
            if (row >= 0) {
                const float4 a = Q4[((size_t)row << 8) + tid];
                const float4 b = SP4[((size_t)(row >> 2) << 8) + tid];
                vv = make_float4(a.x + b.x, a.y + b.y, a.z + b.z, a.w + b.w);
            }
            S4[((4 + i) << 8) + tid] = vv;
        }
    }
    __syncthreads();

    const float SCALE = (float)(77120.0 / 46657.8);   // BG_AREA / FRONT_DIV
    float* o = out + ((size_t)img << 20);
#pragma unroll
    for (int i = 0; i < 4; ++i) {
        const int r = r0 + i;
#pragma unroll
        for (int j = 0; j < 4; ++j) {
            const int c  = tid + (j << 8);
            const int kp = min(c + 160, W - 1);
            const int km = c - 161;
            const float m = (km >= 0) ? 1.f : 0.f;
            const int k  = max(km, 0);
            const float allsum = (S[i][kp] - m * S[i][k]) - (S[4 + i][kp] - m * S[4 + i][k]);
            const float front  = fr[i][j];
            o[((size_t)r << 10) + c] = SCALE * front * __builtin_amdgcn_rcpf(allsum - front);
        }
    }
}

extern "C" void kernel_launch(void* const* d_in, const int* in_sizes, int n_in,
                              void* d_out, int out_size, void* d_ws, size_t ws_size,
                              hipStream_t stream) {
    const float* x = (const float*)d_in[0];
    float* outp = (float*)d_out;
    float* Q   = (float*)d_ws;                           // 16 MB (SAT, seg-local)
    float* SPb = Q + (size_t)IMG * H * W;                // 4 MB (IMG*NSEG*W fp32)

    sat_kernel<<<dim3(IMG * NSEG), dim3(256), 0, stream>>>(x, Q);
    segscan_kernel<<<dim3(64), dim3(256), 0, stream>>>(Q, SPb);
    final_kernel<<<dim3(IMG * (H / 4)), dim3(256), 0, stream>>>(Q, SPb, outp);
}

// Round 11
// 85.777 us; speedup vs baseline: 1.0274x; 1.0274x over previous
//
#include <hip/hip_runtime.h>
#include <hip/hip_bf16.h>

// CFAR via summed-area table — R17: R13 base (swizzles reverted — measured
// neutral in R15/R16) + final restructured to 2 output rows per block:
// 2048 blocks, single 8-row stage pass, ONE barrier (was 3), same 32 KB LDS.
//   sat     : per 4-row segment (1024 blocks): 4 waves compute row prefixes
//             P[0..3] in LDS; one barrier; column-accumulate quad-cols and
//             write segment-local SAT Q (float4). [R13-proven]
//   segscan : SP[img][s][c] = exclusive prefix over segments of Q's segment-
//             last rows. [R13-proven]
//   final   : stage Qg rows (Q + SP fold) for {hi1,lo1,hi3,lo3} x 2 rows in
//             one pass; SAT window math:
//             front  = Qg(r+80,c+80)-Qg(r+80,c-81)-Qg(r-81,c+80)+Qg(r-81,c-81)
//             allsum = same at +-160/161 ; out = SCALE*front/(allsum-front)
// BG_AREA = 321^2-161^2 = 77120 ; FRONT_DIV = 161^2*1.8 = 46657.8

#define IMG 4
#define H 1024
#define W 1024
#define SEGR 4
#define NSEG 256                   // H / SEGR

// ------- Kernel 1: row prefix + segment-local column prefix (SAT) ----------
__global__ __launch_bounds__(256) void sat_kernel(const float* __restrict__ x,
                                                  float* __restrict__ Q) {
    __shared__ float P[4][W];        // 16384 B — per-wave row prefix
    const int wave = threadIdx.x >> 6;
    const int lane = threadIdx.x & 63;
    const int tid  = threadIdx.x;
    const size_t rowbase = (size_t)blockIdx.x << 2;   // flat rows over images

    // ---- phase 1: row prefix into LDS (per wave, own row)
    {
        const float4* xr = reinterpret_cast<const float4*>(x + (rowbase + wave) * W);
        float v[16];
        float4 a0 = xr[(lane << 2) + 0];
        float4 a1 = xr[(lane << 2) + 1];
        float4 a2 = xr[(lane << 2) + 2];
        float4 a3 = xr[(lane << 2) + 3];
        v[0]=a0.x; v[1]=a0.y; v[2]=a0.z; v[3]=a0.w;
        v[4]=a1.x; v[5]=a1.y; v[6]=a1.z; v[7]=a1.w;
        v[8]=a2.x; v[9]=a2.y; v[10]=a2.z; v[11]=a2.w;
        v[12]=a3.x; v[13]=a3.y; v[14]=a3.z; v[15]=a3.w;
        float s = 0.f;
#pragma unroll
        for (int j = 0; j < 16; ++j) { s += v[j]; v[j] = s; }
        float t = s;
#pragma unroll
        for (int d = 1; d < 64; d <<= 1) {
            float u = __shfl_up(t, d, 64);
            if (lane >= d) t += u;
        }
        const float off = t - s;        // exclusive prefix of lane totals
#pragma unroll
        for (int j = 0; j < 16; ++j) v[j] += off;

        float4* Pr = reinterpret_cast<float4*>(P[wave]);
        Pr[(lane << 2) + 0] = make_float4(v[0], v[1], v[2], v[3]);
        Pr[(lane << 2) + 1] = make_float4(v[4], v[5], v[6], v[7]);
        Pr[(lane << 2) + 2] = make_float4(v[8], v[9], v[10], v[11]);
        Pr[(lane << 2) + 3] = make_float4(v[12], v[13], v[14], v[15]);
    }
    __syncthreads();   // the only barrier

    // ---- phase 2: column prefix over the 4 rows; float4 LDS reads + stores
    float4 acc = make_float4(0.f, 0.f, 0.f, 0.f);
    float4* Qo = reinterpret_cast<float4*>(Q) + (rowbase << 8) + tid;
#pragma unroll
    for (int rr = 0; rr < SEGR; ++rr) {
        const float4 h = reinterpret_cast<const float4*>(P[rr])[tid];
        acc.x += h.x; acc.y += h.y; acc.z += h.z; acc.w += h.w;
        Qo[(size_t)rr << 8] = acc;
    }
}

// ------- Kernel 2: exclusive scan of segment totals per column -------------
// Seg total of seg t = Q row (4t+3). Block = (img, 64-col group); wave w owns
// segs 64w..64w+63 in registers (coalesced 256 B loads), in-lane exclusive
// scan, cross-wave fixup via LDS. 64 blocks x 256.
__global__ __launch_bounds__(256) void segscan_kernel(const float* __restrict__ Q,
                                                      float* __restrict__ SP) {
    __shared__ float T[4][64];
    const int wave = threadIdx.x >> 6;
    const int lane = threadIdx.x & 63;
    const int img  = blockIdx.x >> 4;                    // 0..3
    const int col  = ((blockIdx.x & 15) << 6) + lane;    // 0..1023

    const float* Qi = Q + ((size_t)img << 20);
    float v[64];
#pragma unroll
    for (int s = 0; s < 64; ++s) {
        const int seg = (wave << 6) + s;
        v[s] = Qi[((size_t)((seg << 2) + 3) << 10) + col];
    }
    float run = 0.f;
#pragma unroll
    for (int s = 0; s < 64; ++s) { const float t = v[s]; v[s] = run; run += t; }
    T[wave][lane] = run;
    __syncthreads();
    float off = 0.f;
    for (int w = 0; w < wave; ++w) off += T[w][lane];    // wave-uniform trip
    float* SPo = SP + ((size_t)img << 18) + col;
#pragma unroll
    for (int s = 0; s < 64; ++s)
        SPo[(size_t)(((wave << 6) + s)) << 10] = v[s] + off;
}

// ------- Kernel 3: final — SAT window diffs, 2 rows/block ------------------
// Block = (img, 2-row group): 2048 blocks x 256 threads, 32 KB LDS.
// Single stage pass (8 rows: hi1 x2 -> S[0..1], lo1 x2 -> S[2..3],
// hi3 x2 -> S[4..5], lo3 x2 -> S[6..7]; per-row clamp/zero as in R13),
// ONE barrier, then all window math.
__global__ __launch_bounds__(256) void final_kernel(const float* __restrict__ Q,
                                                    const float* __restrict__ SP,
                                                    float* __restrict__ out) {
    __shared__ float S[8][W];        // 32768 B
    const int tid = threadIdx.x;
    const int img = blockIdx.x >> 9;
    const int r0  = (blockIdx.x & 511) << 1;

    const float4* Q4  = reinterpret_cast<const float4*>(Q)  + ((size_t)img << 18);
    const float4* SP4 = reinterpret_cast<const float4*>(SP) + ((size_t)img << 16);
    float4* S4 = reinterpret_cast<float4*>(&S[0][0]);

    // ---- stage all 8 rows (R13's per-row clamp/zero pattern)
#pragma unroll
    for (int i = 0; i < 2; ++i) {
        {   // hi1 = min(r0+80+i, 1023)
            const int row = min(r0 + 80 + i, H - 1);
            const float4 a = Q4[((size_t)row << 8) + tid];
            const float4 b = SP4[((size_t)(row >> 2) << 8) + tid];
            S4[(i << 8) + tid] = make_float4(a.x + b.x, a.y + b.y, a.z + b.z, a.w + b.w);
        }
        {   // lo1 = r0-81+i  (may be negative -> zeros)
            const int row = r0 - 81 + i;
            float4 vv = make_float4(0.f, 0.f, 0.f, 0.f);
            if (row >= 0) {
                const float4 a = Q4[((size_t)row << 8) + tid];
                const float4 b = SP4[((size_t)(row >> 2) << 8) + tid];
                vv = make_float4(a.x + b.x, a.y + b.y, a.z + b.z, a.w + b.w);
            }
            S4[((2 + i) << 8) + tid] = vv;
        }
        {   // hi3 = min(r0+160+i, 1023)
            const int row = min(r0 + 160 + i, H - 1);
            const float4 a = Q4[((size_t)row << 8) + tid];
            const float4 b = SP4[((size_t)(row >> 2) << 8) + tid];
            S4[((4 + i) << 8) + tid] = make_float4(a.x + b.x, a.y + b.y, a.z + b.z, a.w + b.w);
        }
        {   // lo3 = r0-161+i
            const int row = r0 - 161 + i;
            float4 vv = make_float4(0.f, 0.f, 0.f, 0.f);
            if (row >= 0) {
                const float4 a = Q4[((size_t)row << 8) + tid];
                const float4 b = SP4[((size_t)(row >> 2) << 8) + tid];
                vv = make_float4(a.x + b.x, a.y + b.y, a.z + b.z, a.w + b.w);
            }
            S4[((6 + i) << 8) + tid] = vv;
        }
    }
    __syncthreads();   // the only barrier

    const float SCALE = (float)(77120.0 / 46657.8);   // BG_AREA / FRONT_DIV
    float* o = out + ((size_t)img << 20);
#pragma unroll
    for (int i = 0; i < 2; ++i) {
        const int r = r0 + i;
#pragma unroll
        for (int j = 0; j < 4; ++j) {
            const int c   = tid + (j << 8);
            const int kp1 = min(c + 80, W - 1);
            const int km1 = c - 81;
            const float m1 = (km1 >= 0) ? 1.f : 0.f;
            const int kk1 = max(km1, 0);
            const float front = (S[i][kp1] - m1 * S[i][kk1])
                              - (S[2 + i][kp1] - m1 * S[2 + i][kk1]);
            const int kp3 = min(c + 160, W - 1);
            const int km3 = c - 161;
            const float m3 = (km3 >= 0) ? 1.f : 0.f;
            const int kk3 = max(km3, 0);
            const float allsum = (S[4 + i][kp3] - m3 * S[4 + i][kk3])
                               - (S[6 + i][kp3] - m3 * S[6 + i][kk3]);
            o[((size_t)r << 10) + c] = SCALE * front * __builtin_amdgcn_rcpf(allsum - front);
        }
    }
}

extern "C" void kernel_launch(void* const* d_in, const int* in_sizes, int n_in,
                              void* d_out, int out_size, void* d_ws, size_t ws_size,
                              hipStream_t stream) {
    const float* x = (const float*)d_in[0];
    float* outp = (float*)d_out;
    float* Q   = (float*)d_ws;                           // 16 MB (SAT, seg-local)
    float* SPb = Q + (size_t)IMG * H * W;                // 4 MB (IMG*NSEG*W fp32)

    sat_kernel<<<dim3(IMG * NSEG), dim3(256), 0, stream>>>(x, Q);
    segscan_kernel<<<dim3(64), dim3(256), 0, stream>>>(Q, SPb);
    final_kernel<<<dim3(IMG * (H / 2)), dim3(256), 0, stream>>>(Q, SPb, outp);
}

// Round 12
// 85.314 us; speedup vs baseline: 1.0329x; 1.0054x over previous
//
#include <hip/hip_runtime.h>
#include <hip/hip_bf16.h>

// CFAR via summed-area table — R18: R17 + final stages band DIFFERENCES
// (F1 = Qg(hi1)-Qg(lo1), F3 = Qg(hi3)-Qg(lo3)) instead of 8 raw rows:
// LDS 32->16 KB, math LDS reads halved, +80/+160 ends vectorized (adjacent
// 4-col ownership -> aligned float4 LDS reads), float4 output stores.
//   sat     : per 4-row segment (1024 blocks): 4 waves compute row prefixes
//             P[0..3] in LDS; one barrier; column-accumulate quad-cols and
//             write segment-local SAT Q (float4). [R13-proven]
//   segscan : SP[img][s][c] = exclusive prefix over segments of Q's segment-
//             last rows. [R13-proven]
//   final   : F1/F3 band rows for 2 output rows; ONE barrier;
//             front = F1[c+80] - m*F1[c-81], allsum = F3[c+160] - m*F3[c-161],
//             out = SCALE*front/(allsum-front)
// BG_AREA = 321^2-161^2 = 77120 ; FRONT_DIV = 161^2*1.8 = 46657.8

#define IMG 4
#define H 1024
#define W 1024
#define SEGR 4
#define NSEG 256                   // H / SEGR

// ------- Kernel 1: row prefix + segment-local column prefix (SAT) ----------
__global__ __launch_bounds__(256) void sat_kernel(const float* __restrict__ x,
                                                  float* __restrict__ Q) {
    __shared__ float P[4][W];        // 16384 B — per-wave row prefix
    const int wave = threadIdx.x >> 6;
    const int lane = threadIdx.x & 63;
    const int tid  = threadIdx.x;
    const size_t rowbase = (size_t)blockIdx.x << 2;   // flat rows over images

    // ---- phase 1: row prefix into LDS (per wave, own row)
    {
        const float4* xr = reinterpret_cast<const float4*>(x + (rowbase + wave) * W);
        float v[16];
        float4 a0 = xr[(lane << 2) + 0];
        float4 a1 = xr[(lane << 2) + 1];
        float4 a2 = xr[(lane << 2) + 2];
        float4 a3 = xr[(lane << 2) + 3];
        v[0]=a0.x; v[1]=a0.y; v[2]=a0.z; v[3]=a0.w;
        v[4]=a1.x; v[5]=a1.y; v[6]=a1.z; v[7]=a1.w;
        v[8]=a2.x; v[9]=a2.y; v[10]=a2.z; v[11]=a2.w;
        v[12]=a3.x; v[13]=a3.y; v[14]=a3.z; v[15]=a3.w;
        float s = 0.f;
#pragma unroll
        for (int j = 0; j < 16; ++j) { s += v[j]; v[j] = s; }
        float t = s;
#pragma unroll
        for (int d = 1; d < 64; d <<= 1) {
            float u = __shfl_up(t, d, 64);
            if (lane >= d) t += u;
        }
        const float off = t - s;        // exclusive prefix of lane totals
#pragma unroll
        for (int j = 0; j < 16; ++j) v[j] += off;

        float4* Pr = reinterpret_cast<float4*>(P[wave]);
        Pr[(lane << 2) + 0] = make_float4(v[0], v[1], v[2], v[3]);
        Pr[(lane << 2) + 1] = make_float4(v[4], v[5], v[6], v[7]);
        Pr[(lane << 2) + 2] = make_float4(v[8], v[9], v[10], v[11]);
        Pr[(lane << 2) + 3] = make_float4(v[12], v[13], v[14], v[15]);
    }
    __syncthreads();   // the only barrier

    // ---- phase 2: column prefix over the 4 rows; float4 LDS reads + stores
    float4 acc = make_float4(0.f, 0.f, 0.f, 0.f);
    float4* Qo = reinterpret_cast<float4*>(Q) + (rowbase << 8) + tid;
#pragma unroll
    for (int rr = 0; rr < SEGR; ++rr) {
        const float4 h = reinterpret_cast<const float4*>(P[rr])[tid];
        acc.x += h.x; acc.y += h.y; acc.z += h.z; acc.w += h.w;
        Qo[(size_t)rr << 8] = acc;
    }
}

// ------- Kernel 2: exclusive scan of segment totals per column -------------
// Seg total of seg t = Q row (4t+3). Block = (img, 64-col group); wave w owns
// segs 64w..64w+63 in registers (coalesced 256 B loads), in-lane exclusive
// scan, cross-wave fixup via LDS. 64 blocks x 256.
__global__ __launch_bounds__(256) void segscan_kernel(const float* __restrict__ Q,
                                                      float* __restrict__ SP) {
    __shared__ float T[4][64];
    const int wave = threadIdx.x >> 6;
    const int lane = threadIdx.x & 63;
    const int img  = blockIdx.x >> 4;                    // 0..3
    const int col  = ((blockIdx.x & 15) << 6) + lane;    // 0..1023

    const float* Qi = Q + ((size_t)img << 20);
    float v[64];
#pragma unroll
    for (int s = 0; s < 64; ++s) {
        const int seg = (wave << 6) + s;
        v[s] = Qi[((size_t)((seg << 2) + 3) << 10) + col];
    }
    float run = 0.f;
#pragma unroll
    for (int s = 0; s < 64; ++s) { const float t = v[s]; v[s] = run; run += t; }
    T[wave][lane] = run;
    __syncthreads();
    float off = 0.f;
    for (int w = 0; w < wave; ++w) off += T[w][lane];    // wave-uniform trip
    float* SPo = SP + ((size_t)img << 18) + col;
#pragma unroll
    for (int s = 0; s < 64; ++s)
        SPo[(size_t)(((wave << 6) + s)) << 10] = v[s] + off;
}

// ------- Kernel 3: final — band-difference window math, 2 rows/block -------
// Block = (img, 2-row group): 2048 blocks x 256 threads, 16 KB LDS.
// Stage F1[i] = Qg(hi1_i) - Qg(lo1_i), F3[i] = Qg(hi3_i) - Qg(lo3_i)
// (row clamp/zero at stage time); ONE barrier; thread owns 4 ADJACENT
// columns -> +80/+160 ends are aligned float4 LDS reads; float4 stores.
__global__ __launch_bounds__(256) void final_kernel(const float* __restrict__ Q,
                                                    const float* __restrict__ SP,
                                                    float* __restrict__ out) {
    __shared__ float F[4][W];        // 16384 B: F1[0..1], F3[0..1]
    const int tid = threadIdx.x;
    const int img = blockIdx.x >> 9;
    const int r0  = (blockIdx.x & 511) << 1;

    const float4* Q4  = reinterpret_cast<const float4*>(Q)  + ((size_t)img << 18);
    const float4* SP4 = reinterpret_cast<const float4*>(SP) + ((size_t)img << 16);
    float4* F4 = reinterpret_cast<float4*>(&F[0][0]);

    // ---- stage band differences (4 rows total)
#pragma unroll
    for (int i = 0; i < 2; ++i) {
        {   // F1[i] = Qg(min(r0+80+i,1023)) - Qg(r0-81+i | 0)
            const int rh = min(r0 + 80 + i, H - 1);
            const float4 a = Q4[((size_t)rh << 8) + tid];
            const float4 b = SP4[((size_t)(rh >> 2) << 8) + tid];
            float hx = a.x + b.x, hy = a.y + b.y, hz = a.z + b.z, hw = a.w + b.w;
            const int rl = r0 - 81 + i;
            if (rl >= 0) {
                const float4 c = Q4[((size_t)rl << 8) + tid];
                const float4 d = SP4[((size_t)(rl >> 2) << 8) + tid];
                hx -= c.x + d.x; hy -= c.y + d.y; hz -= c.z + d.z; hw -= c.w + d.w;
            }
            F4[(i << 8) + tid] = make_float4(hx, hy, hz, hw);
        }
        {   // F3[i] = Qg(min(r0+160+i,1023)) - Qg(r0-161+i | 0)
            const int rh = min(r0 + 160 + i, H - 1);
            const float4 a = Q4[((size_t)rh << 8) + tid];
            const float4 b = SP4[((size_t)(rh >> 2) << 8) + tid];
            float hx = a.x + b.x, hy = a.y + b.y, hz = a.z + b.z, hw = a.w + b.w;
            const int rl = r0 - 161 + i;
            if (rl >= 0) {
                const float4 c = Q4[((size_t)rl << 8) + tid];
                const float4 d = SP4[((size_t)(rl >> 2) << 8) + tid];
                hx -= c.x + d.x; hy -= c.y + d.y; hz -= c.z + d.z; hw -= c.w + d.w;
            }
            F4[((2 + i) << 8) + tid] = make_float4(hx, hy, hz, hw);
        }
    }
    __syncthreads();   // the only barrier

    const float SCALE = (float)(77120.0 / 46657.8);   // BG_AREA / FRONT_DIV
    float4* o4 = reinterpret_cast<float4*>(out + ((size_t)img << 20));
    const int c0 = tid << 2;                          // first owned column
#pragma unroll
    for (int i = 0; i < 2; ++i) {
        const int r = r0 + i;
        const float* F1 = F[i];
        const float* F3 = F[2 + i];

        float p1[4], p3[4];
        if (tid <= 235) {           // c0+83 <= 1023: aligned float4 at c0+80
            const float4 v = *reinterpret_cast<const float4*>(F1 + c0 + 80);
            p1[0] = v.x; p1[1] = v.y; p1[2] = v.z; p1[3] = v.w;
        } else {
#pragma unroll
            for (int j = 0; j < 4; ++j) p1[j] = F1[min(c0 + j + 80, W - 1)];
        }
        if (tid <= 215) {           // c0+163 <= 1023: aligned float4 at c0+160
            const float4 v = *reinterpret_cast<const float4*>(F3 + c0 + 160);
            p3[0] = v.x; p3[1] = v.y; p3[2] = v.z; p3[3] = v.w;
        } else {
#pragma unroll
            for (int j = 0; j < 4; ++j) p3[j] = F3[min(c0 + j + 160, W - 1)];
        }

        float ov[4];
#pragma unroll
        for (int j = 0; j < 4; ++j) {
            const int k1 = c0 + j - 81;
            const int k3 = c0 + j - 161;
            const float front  = p1[j] - ((k1 >= 0) ? F1[k1] : 0.f);
            const float allsum = p3[j] - ((k3 >= 0) ? F3[k3] : 0.f);
            ov[j] = SCALE * front * __builtin_amdgcn_rcpf(allsum - front);
        }
        o4[((size_t)r << 8) + tid] = make_float4(ov[0], ov[1], ov[2], ov[3]);
    }
}

extern "C" void kernel_launch(void* const* d_in, const int* in_sizes, int n_in,
                              void* d_out, int out_size, void* d_ws, size_t ws_size,
                              hipStream_t stream) {
    const float* x = (const float*)d_in[0];
    float* outp = (float*)d_out;
    float* Q   = (float*)d_ws;                           // 16 MB (SAT, seg-local)
    float* SPb = Q + (size_t)IMG * H * W;                // 4 MB (IMG*NSEG*W fp32)

    sat_kernel<<<dim3(IMG * NSEG), dim3(256), 0, stream>>>(x, Q);
    segscan_kernel<<<dim3(64), dim3(256), 0, stream>>>(Q, SPb);
    final_kernel<<<dim3(IMG * (H / 2)), dim3(256), 0, stream>>>(Q, SPb, outp);
}